// Round 12
// baseline (140.490 us; speedup 1.0000x reference)
//
#include <hip/hip_runtime.h>
#include <float.h>

// z: (64,32,32,64) fp32 -> N=65536 rows, D=64 ; codebook: (1024,64) fp32
// out concat fp32: zq [N*64] | tokens-as-float [N] | codebook [1024*64]
constexpr int D     = 64;
constexpr int V     = 1024;
constexpr int NROWS = 65536;
// Split-f16 screen (zh*ch + zh*cl + zl*ch); MARGIN certifies argmin.
// Same screen+margin passed with absmax=0 in rounds 4, 8, 9, 10, 11.
constexpr float MARGIN = 0.01f;

typedef _Float16 half8 __attribute__((ext_vector_type(8)));
typedef float    f32x4 __attribute__((ext_vector_type(4)));

// ---------------- prep: convert codebook ONCE (r7-diag-verified bit-exact) ----------------
__global__ __launch_bounds__(256) void vq_prep(
    const float* __restrict__ cb, _Float16* __restrict__ wsH,
    _Float16* __restrict__ wsL, float* __restrict__ c2,
    float* __restrict__ cbout, int* __restrict__ cnt) {
  const int t = blockIdx.x * 256 + threadIdx.x;  // grid = 4 blocks -> 1024 threads
  if (t == 0) cnt[0] = 0;                        // replaces the memset dispatch
#pragma unroll
  for (int i = 0; i < 16; ++i)   // coalesced codebook passthrough
    ((float4*)cbout)[i * 1024 + t] = ((const float4*)cb)[i * 1024 + t];

  const int cw = t;
  const float* src = cb + (size_t)cw * D;
  float part = 0.f;
#pragma unroll
  for (int chunk = 0; chunk < 8; ++chunk) {
    float4 q0 = ((const float4*)(src + chunk * 8))[0];
    float4 q1 = ((const float4*)(src + chunk * 8))[1];
    float xs[8] = {q0.x, q0.y, q0.z, q0.w, q1.x, q1.y, q1.z, q1.w};
    half8 hh, hl;
#pragma unroll
    for (int e = 0; e < 8; ++e) {
      _Float16 hi = (_Float16)xs[e];
      hh[e] = hi;
      hl[e] = (_Float16)(xs[e] - (float)hi);
      part  = fmaf(xs[e], xs[e], part);
    }
    *(half8*)&wsH[((size_t)chunk * V + cw) * 8] = hh;
    *(half8*)&wsL[((size_t)chunk * V + cw) * 8] = hl;
  }
  c2[cw] = part;
}

// ---------------- screen: r11 body VERBATIM, split-V across block pairs ----------------
// 2048 blocks x 256 threads: block b -> rows (b>>1)*64..+64, codeword half b&1
// (phases [8h, 8h+8) of 16). r11's grid of 1024 capped residency at 4 blocks/CU;
// 2048 blocks refill to the 6-block launch-bounds cap. Emits per-row partials
// (b1,b2,i1) per half; vq_merge combines. Per-distance math, visit order and
// tie-breaks bit-identical to r11 (passed absmax=0).
__global__ __launch_bounds__(256, 6) void vq_screen(
    const float* __restrict__ z,
    const _Float16* __restrict__ wsH, const _Float16* __restrict__ wsL,
    const float* __restrict__ c2g,
    float* __restrict__ pB1, float* __restrict__ pB2, int* __restrict__ pI1) {
  __shared__ __align__(16) _Float16 sBh[8][64][8];   // 8 KiB
  __shared__ __align__(16) _Float16 sBl[8][64][8];   // 8 KiB
  __shared__ __align__(16) float sC2[64];

  const int tid  = threadIdx.x;
  const int lane = tid & 63;
  const int wv   = tid >> 6;        // wave 0..3
  const int l15  = lane & 15;
  const int quad = lane >> 4;
  const int half = blockIdx.x & 1;
  const int rowbase = (blockIdx.x >> 1) * 64 + wv * 16;

  // A fragments hi/lo: row rowbase + l15, k = quad*8 + j (+32*h)  [r4-proven code]
  half8 afh[2], afl[2];
  {
    const float* zr = z + (size_t)(rowbase + l15) * D;
#pragma unroll
    for (int h = 0; h < 2; ++h) {
      const float4* p = (const float4*)(zr + h * 32 + quad * 8);
      float4 q0 = p[0], q1 = p[1];
      float xs[8] = {q0.x, q0.y, q0.z, q0.w, q1.x, q1.y, q1.z, q1.w};
      half8 ah, al;
#pragma unroll
      for (int e = 0; e < 8; ++e) {
        _Float16 hi = (_Float16)xs[e];
        ah[e] = hi;
        al[e] = (_Float16)(xs[e] - (float)hi);
      }
      afh[h] = ah; afl[h] = al;
    }
  }

  float b1[4], b2[4]; int i1[4];
#pragma unroll
  for (int r = 0; r < 4; ++r) { b1[r] = FLT_MAX; b2[r] = FLT_MAX; i1[r] = 0; }

  for (int pp = 0; pp < 8; ++pp) {
    const int phase = half * 8 + pp;   // this half's 8 of the 16 phases
    __syncthreads();  // previous compute done before LDS overwrite
    // ---- stage 64 codewords (hi+lo, 16 KiB): 1024 x 16B over 256 threads ----
#pragma unroll
    for (int i = 0; i < 4; ++i) {
      const int idx   = i * 256 + tid;
      const int seg   = idx >> 6;       // 0..15 (0..7 hi, 8..15 lo)
      const int off   = idx & 63;
      const int chunk = seg & 7;
      const _Float16* srcb = (seg < 8) ? wsH : wsL;
      const half8 v = *(const half8*)&srcb[((size_t)chunk * V + phase * 64 + off) * 8];
      if (seg < 8) *(half8*)&sBh[chunk][off][0] = v;
      else         *(half8*)&sBl[chunk][off][0] = v;
    }
    if (tid < 16) {
      float4 q = ((const float4*)(c2g + phase * 64))[tid];
      *(float4*)&sC2[tid * 4] = q;
    }
    __syncthreads();
    // ---- 4 col-tiles of 16 codewords each ----
#pragma unroll 2
    for (int tl = 0; tl < 4; ++tl) {
      const int cwl  = tl * 16 + l15;
      const int vcol = phase * 64 + cwl;
      const float c2v = sC2[cwl];
      half8 bh0 = *(const half8*)&sBh[quad][cwl][0];      // k = quad*8+j
      half8 bh1 = *(const half8*)&sBh[4 + quad][cwl][0];  // k = 32+quad*8+j
      half8 bl0 = *(const half8*)&sBl[quad][cwl][0];
      half8 bl1 = *(const half8*)&sBl[4 + quad][cwl][0];
      f32x4 acc = {0.f, 0.f, 0.f, 0.f};
      acc = __builtin_amdgcn_mfma_f32_16x16x32_f16(afh[0], bh0, acc, 0, 0, 0);
      acc = __builtin_amdgcn_mfma_f32_16x16x32_f16(afh[1], bh1, acc, 0, 0, 0);
      acc = __builtin_amdgcn_mfma_f32_16x16x32_f16(afh[0], bl0, acc, 0, 0, 0);
      acc = __builtin_amdgcn_mfma_f32_16x16x32_f16(afh[1], bl1, acc, 0, 0, 0);
      acc = __builtin_amdgcn_mfma_f32_16x16x32_f16(afl[0], bh0, acc, 0, 0, 0);
      acc = __builtin_amdgcn_mfma_f32_16x16x32_f16(afl[1], bh1, acc, 0, 0, 0);
#pragma unroll
      for (int r = 0; r < 4; ++r) {
        float m0 = fmaf(-2.f, acc[r], c2v);
        bool  c0 = m0 < b1[r];
        b2[r] = fminf(b2[r], fmaxf(m0, b1[r]));
        b1[r] = c0 ? m0 : b1[r];
        i1[r] = c0 ? vcol : i1[r];
      }
    }
  }

  // ---- reduce over the 16 col-lanes of each quad group (C: row=quad*4+r, col=l15) ----
#pragma unroll
  for (int r = 0; r < 4; ++r) {
    float v1 = b1[r], v2 = b2[r]; int ix = i1[r];
#pragma unroll
    for (int s = 1; s < 16; s <<= 1) {
      float ov1 = __shfl_xor(v1, s);
      float ov2 = __shfl_xor(v2, s);
      int   oix = __shfl_xor(ix, s);
      bool take = (ov1 < v1) || (ov1 == v1 && oix < ix);  // first-occurrence ties
      float worse = take ? v1 : ov1;
      v2 = fminf(fminf(v2, ov2), worse);
      v1 = take ? ov1 : v1;
      ix = take ? oix : ix;
    }
    b1[r] = v1; b2[r] = v2; i1[r] = ix;
  }

  // ---- emit per-row partials for this half ----
  if (l15 == 0) {
#pragma unroll
    for (int r = 0; r < 4; ++r) {
      const int grow = rowbase + quad * 4 + r;
      pB1[half * NROWS + grow] = b1[r];
      pB2[half * NROWS + grow] = b2[r];
      pI1[half * NROWS + grow] = i1[r];
    }
  }
}

// ---------------- merge: combine halves, margin check, tok + zq + flag list ----------------
// 2-way merge is the same comparator the in-wave butterfly used (proven);
// half-1 indices all > half-0, so b1m/b2m/i1m equal r11's sequential result.
__global__ __launch_bounds__(256) void vq_merge(
    const float* __restrict__ pB1, const float* __restrict__ pB2,
    const int* __restrict__ pI1, const float* __restrict__ cb,
    float* __restrict__ zq, float* __restrict__ tok,
    int* __restrict__ cnt, int* __restrict__ list) {
  __shared__ int sWin[256];
  const int tid = threadIdx.x;
  const int row = blockIdx.x * 256 + tid;   // grid = 256 blocks

  float v1a = pB1[row];         float v2a = pB2[row];         int ixa = pI1[row];
  float v1b = pB1[NROWS + row]; float v2b = pB2[NROWS + row]; int ixb = pI1[NROWS + row];
  bool take  = (v1b < v1a) || (v1b == v1a && ixb < ixa);
  float worse = take ? v1a : v1b;
  float v2 = fminf(fminf(v2a, v2b), worse);
  float v1 = take ? v1b : v1a;
  int   ix = take ? ixb : ixa;

  tok[row]  = (float)ix;
  sWin[tid] = ix;
  if (v2 - v1 < MARGIN) {           // screen can't certify argmin
    int s = atomicAdd(cnt, 1);      // ~300 total atomics chip-wide
    list[s] = row;
  }
  __syncthreads();

  // zq gather (r11-proven pattern, scaled): 256 rows x 16 chunks = 4096 float4
  const int rb = blockIdx.x * 256;
#pragma unroll
  for (int i = 0; i < 16; ++i) {
    int cid = i * 256 + tid;
    int r = cid >> 4, seg = cid & 15;
    float4 val = *(const float4*)(cb + (size_t)sWin[r] * D + seg * 4);
    *(float4*)(zq + (size_t)(rb + r) * D + seg * 4) = val;
  }
}

// ---------------- exact fp32 fallback: VERBATIM round-2 block-per-row (proven) ----------------
__global__ __launch_bounds__(256) void vq_fallback(
    const float* __restrict__ z, const float* __restrict__ cb,
    const int* __restrict__ cnt, const int* __restrict__ list,
    float* __restrict__ zq, float* __restrict__ tok) {
  __shared__ float sv[256];
  __shared__ int   si[256];
  const int t = threadIdx.x;
  const int n = cnt[0];
  for (int it = blockIdx.x; it < n; it += gridDim.x) {
    int row = __builtin_amdgcn_readfirstlane(list[it]);
    const float* zr = z + (size_t)row * D;
    float zreg[D];
#pragma unroll
    for (int i = 0; i < D / 4; ++i) {
      float4 q = ((const float4*)zr)[i];
      zreg[4 * i] = q.x; zreg[4 * i + 1] = q.y; zreg[4 * i + 2] = q.z; zreg[4 * i + 3] = q.w;
    }
    float d1 = 0.f;
#pragma unroll
    for (int i = 0; i < D; ++i) d1 = fmaf(zreg[i], zreg[i], d1);
    float best = FLT_MAX; int bidx = 0;
    for (int c = 0; c < 4; ++c) {
      int v = t + 256 * c;
      const float* cp = cb + (size_t)v * D;
      float acc = 0.f, cc = 0.f;
#pragma unroll
      for (int dd = 0; dd < D; ++dd) {
        acc = fmaf(zreg[dd], cp[dd], acc);
        cc  = fmaf(cp[dd], cp[dd], cc);
      }
      float dist = (d1 + cc) - 2.f * acc;
      if (dist < best) { best = dist; bidx = v; }
    }
    sv[t] = best; si[t] = bidx;
    __syncthreads();
    for (int s = 128; s > 0; s >>= 1) {
      if (t < s) {
        float v2 = sv[t + s]; int i2 = si[t + s];
        if (v2 < sv[t] || (v2 == sv[t] && i2 < si[t])) { sv[t] = v2; si[t] = i2; }
      }
      __syncthreads();
    }
    int win = si[0];
    if (t == 0) tok[row] = (float)win;
    if (t < 16) {
      float4 q = ((const float4*)(cb + (size_t)win * D))[t];
      ((float4*)(zq + (size_t)row * D))[t] = q;
    }
    __syncthreads();  // sv/si reused next iteration
  }
}

extern "C" void kernel_launch(void* const* d_in, const int* in_sizes, int n_in,
                              void* d_out, int out_size, void* d_ws, size_t ws_size,
                              hipStream_t stream) {
  const float* z  = (const float*)d_in[0];
  const float* cb = (const float*)d_in[1];

  float* out = (float*)d_out;
  float* zq  = out;                      // [NROWS*D]
  float* tok = out + (size_t)NROWS * D;  // [NROWS]
  float* cbo = tok + NROWS;              // [V*D]

  // ws layout (r9 fill counter shows ws = 256 MiB; this uses 2.5 MiB):
  // wsH 128K | wsL 128K | c2 4K | cnt | list 256K | pB1 512K | pB2 512K | pI1 512K
  char* wsb = (char*)d_ws;
  _Float16* wsH  = (_Float16*)(wsb + 0);
  _Float16* wsL  = (_Float16*)(wsb + 131072);
  float*    c2   = (float*)(wsb + 262144);
  int*      cnt  = (int*)(wsb + 266240);
  int*      list = (int*)(wsb + 266496);
  float*    pB1  = (float*)(wsb + 1048576);
  float*    pB2  = (float*)(wsb + 1572864);
  int*      pI1  = (int*)(wsb + 2097152);

  vq_prep<<<V / 256, 256, 0, stream>>>(cb, wsH, wsL, c2, cbo, cnt);
  vq_screen<<<2048, 256, 0, stream>>>(z, wsH, wsL, c2, pB1, pB2, pI1);
  vq_merge<<<NROWS / 256, 256, 0, stream>>>(pB1, pB2, pI1, cb, zq, tok, cnt, list);
  vq_fallback<<<1024, 256, 0, stream>>>(z, cb, cnt, list, zq, tok);
}